// Round 7
// baseline (509.713 us; speedup 1.0000x reference)
//
#include <hip/hip_runtime.h>

#define NT 512
#define ROWLEN 16384
#define PT 8      // u32x4 per thread: 8 * 4 * 512 = 16384 floats per row
#define CAP 4096  // candidate buffer entries (16 KB)
#define RPB 2     // rows per block (register ping-pong prefetch)

typedef unsigned int u32x4 __attribute__((ext_vector_type(4)));

// Barrier draining ONLY LDS ops (lgkmcnt), not vmem — prefetch loads and
// NT output stores stay in flight across hist/select phases.
__device__ __forceinline__ void sync_lds() {
  asm volatile("s_waitcnt lgkmcnt(0)" ::: "memory");
  __builtin_amdgcn_s_barrier();
  asm volatile("" ::: "memory");
}
__device__ __forceinline__ void wait_lds() {
  asm volatile("s_waitcnt lgkmcnt(0)" ::: "memory");
}

// Wave-redundant hierarchical descending select over NB bins. All 64 lanes
// of the calling wave return identical {bin, rem} with
//   count(bins > bin) < krem <= count(bins >= bin), rem = krem - count(bins > bin).
// No LDS writes, no barriers, no register arrays.
template<int NB>
__device__ __forceinline__ void wave_select(const unsigned* hist, unsigned krem,
                                            unsigned lane, unsigned& binOut,
                                            unsigned& remOut) {
  constexpr int BPL = NB / 64;  // bins per lane
  const unsigned base = lane * BPL;
  unsigned s = 0;
#pragma unroll
  for (int i = 0; i < BPL; i++) s += hist[base + i];
  // inclusive suffix-sum across lanes (sum over lanes >= lane)
  unsigned suf = s;
#pragma unroll
  for (int off = 1; off < 64; off <<= 1) {
    unsigned v = __shfl_down(suf, off);
    if (lane + off < 64) suf += v;
  }
  const unsigned above = suf - s;  // count in lanes strictly above mine
  unsigned pack = (above < krem && above + s >= krem)
                      ? (0x80000000u | (lane << 24) | above) : 0u;
#pragma unroll
  for (int off = 1; off < 64; off <<= 1) pack |= __shfl_xor(pack, off);
  const unsigned L      = (pack >> 24) & 63u;
  const unsigned aboveL = pack & 0xFFFFFFu;

  // stage 2: lanes 0..BPL-1 take one bin each of lane L's range
  unsigned c2 = (lane < BPL) ? hist[L * BPL + lane] : 0u;
  unsigned suf2 = c2;
#pragma unroll
  for (int off = 1; off < 64; off <<= 1) {
    unsigned v = __shfl_down(suf2, off);
    if (lane + off < 64) suf2 += v;
  }
  const unsigned above2 = aboveL + (suf2 - c2);
  unsigned pack2 = (above2 < krem && above2 + c2 >= krem)
                       ? (0x80000000u | (lane << 24) | (krem - above2)) : 0u;
#pragma unroll
  for (int off = 1; off < 64; off <<= 1) pack2 |= __shfl_xor(pack2, off);
  binOut = L * BPL + ((pack2 >> 24) & 63u);
  remOut = pack2 & 0xFFFFFFu;
}

__device__ __forceinline__ void process_row(
    u32x4 (&d)[PT], unsigned k, unsigned tid, unsigned lane, unsigned wid,
    unsigned* hist1, unsigned* hist2, unsigned* hist3, unsigned* cand,
    unsigned* sel, unsigned* cnt, u32x4* orow) {
  // ---- zero all histograms ----
#pragma unroll
  for (int i = 0; i < 2048 / NT; i++) hist1[tid + i * NT] = 0u;
#pragma unroll
  for (int i = 0; i < 1024 / NT; i++) { hist2[tid + i * NT] = 0u; hist3[tid + i * NT] = 0u; }
  if (tid == 0) *cnt = 0u;
  sync_lds();  // [1]

  // ---- level 1: 2048 bins over a>>21, a = u<<1 (sign dropped) ----
#pragma unroll
  for (int j = 0; j < PT; j++) {
    atomicAdd(&hist1[(d[j].x << 1) >> 21], 1u);
    atomicAdd(&hist1[(d[j].y << 1) >> 21], 1u);
    atomicAdd(&hist1[(d[j].z << 1) >> 21], 1u);
    atomicAdd(&hist1[(d[j].w << 1) >> 21], 1u);
  }
  sync_lds();  // [2]

  unsigned P1, r1;
  wave_select<2048>(hist1, k, lane, P1, r1);  // every wave, redundant, barrier-free

  // ---- gather candidates: per-thread count -> wave prefix -> 1 atomic/wave ----
  unsigned mc = 0;
#pragma unroll
  for (int j = 0; j < PT; j++) {
    mc += ((d[j].x << 1) >> 21) == P1;
    mc += ((d[j].y << 1) >> 21) == P1;
    mc += ((d[j].z << 1) >> 21) == P1;
    mc += ((d[j].w << 1) >> 21) == P1;
  }
  unsigned pre = mc;
#pragma unroll
  for (int off = 1; off < 64; off <<= 1) {
    unsigned v = __shfl_up(pre, off);
    if (lane >= off) pre += v;
  }
  const unsigned wtotal = __shfl(pre, 63);
  unsigned idx = 0;
  if (lane == 0 && wtotal) idx = atomicAdd(cnt, wtotal);
  idx = __builtin_amdgcn_readfirstlane(idx) + (pre - mc);
#pragma unroll
  for (int j = 0; j < PT; j++) {
    unsigned a;
    a = d[j].x << 1; if ((a >> 21) == P1) { if (idx < CAP) cand[idx] = a; idx++; }
    a = d[j].y << 1; if ((a >> 21) == P1) { if (idx < CAP) cand[idx] = a; idx++; }
    a = d[j].z << 1; if ((a >> 21) == P1) { if (idx < CAP) cand[idx] = a; idx++; }
    a = d[j].w << 1; if ((a >> 21) == P1) { if (idx < CAP) cand[idx] = a; idx++; }
  }
  sync_lds();  // [3]
  const unsigned n = *cnt;

  unsigned Va;
  if (n <= CAP) {
    // ---- levels 2+3 entirely in wave 0, wave-local sync only ----
    if (wid == 0) {
      for (unsigned i = lane; i < n; i += 64)
        atomicAdd(&hist2[(cand[i] >> 11) & 0x3FFu], 1u);
      wait_lds();
      unsigned P2, r2;
      wave_select<1024>(hist2, r1, lane, P2, r2);
      for (unsigned i = lane; i < n; i += 64) {
        unsigned a = cand[i];
        if (((a >> 11) & 0x3FFu) == P2) atomicAdd(&hist3[(a >> 1) & 0x3FFu], 1u);
      }
      wait_lds();
      unsigned b3, r3;
      wave_select<1024>(hist3, r2, lane, b3, r3);
      if (lane == 0) sel[0] = (P1 << 21) | (P2 << 11) | (b3 << 1);
    }
    sync_lds();  // [4] Va visible; also fences hist reads vs next-row zeroing
    Va = sel[0];
  } else {
    // ---- overflow fallback (statistically never; uniform branch) ----
#pragma unroll
    for (int j = 0; j < PT; j++) {
      unsigned a;
      a = d[j].x << 1; if ((a >> 21) == P1) atomicAdd(&hist2[(a >> 11) & 0x3FFu], 1u);
      a = d[j].y << 1; if ((a >> 21) == P1) atomicAdd(&hist2[(a >> 11) & 0x3FFu], 1u);
      a = d[j].z << 1; if ((a >> 21) == P1) atomicAdd(&hist2[(a >> 11) & 0x3FFu], 1u);
      a = d[j].w << 1; if ((a >> 21) == P1) atomicAdd(&hist2[(a >> 11) & 0x3FFu], 1u);
    }
    sync_lds();
    unsigned P2, r2;
    wave_select<1024>(hist2, r1, lane, P2, r2);
    const unsigned P12 = (P1 << 10) | P2;
#pragma unroll
    for (int j = 0; j < PT; j++) {
      unsigned a;
      a = d[j].x << 1; if ((a >> 11) == P12) atomicAdd(&hist3[(a >> 1) & 0x3FFu], 1u);
      a = d[j].y << 1; if ((a >> 11) == P12) atomicAdd(&hist3[(a >> 1) & 0x3FFu], 1u);
      a = d[j].z << 1; if ((a >> 11) == P12) atomicAdd(&hist3[(a >> 1) & 0x3FFu], 1u);
      a = d[j].w << 1; if ((a >> 11) == P12) atomicAdd(&hist3[(a >> 1) & 0x3FFu], 1u);
    }
    sync_lds();
    unsigned b3, r3;
    wave_select<1024>(hist3, r2, lane, b3, r3);
    Va = (P1 << 21) | (P2 << 11) | (b3 << 1);
    sync_lds();  // fence hist reads vs next-row zeroing
  }

  // ---- mask + nontemporal store (flies across next row's phases) ----
#pragma unroll
  for (int j = 0; j < PT; j++) {
    u32x4 v = d[j], o;
    o.x = ((v.x << 1) >= Va) ? v.x : 0u;
    o.y = ((v.y << 1) >= Va) ? v.y : 0u;
    o.z = ((v.z << 1) >= Va) ? v.z : 0u;
    o.w = ((v.w << 1) >= Va) ? v.w : 0u;
    __builtin_nontemporal_store(o, &orow[tid + j * NT]);
  }
}

// No min-waves clamp: VGPR cap 256 — the data arrays (64 VGPRs) must NOT
// spill (round-6: (NT,4) cap forced VGPR_Count=64 -> scratch, 175 us).
__global__ __launch_bounds__(NT)
void topk_act_kernel(const float* __restrict__ x, float* __restrict__ out,
                     const int* __restrict__ kp) {
  __shared__ unsigned hist1[2048];
  __shared__ unsigned hist2[1024];
  __shared__ unsigned hist3[1024];
  __shared__ unsigned cand[CAP];
  __shared__ unsigned sel[1];
  __shared__ unsigned cnt;

  const unsigned tid = threadIdx.x;
  const unsigned lane = tid & 63u;
  const unsigned wid = tid >> 6;
  const unsigned k = (unsigned)*kp;
  const size_t row0 = (size_t)blockIdx.x * RPB;

  const u32x4* __restrict__ xr0 = reinterpret_cast<const u32x4*>(x + row0 * (size_t)ROWLEN);
  const u32x4* __restrict__ xr1 = reinterpret_cast<const u32x4*>(x + (row0 + 1) * (size_t)ROWLEN);

  u32x4 dA[PT], dB[PT];
#pragma unroll
  for (int j = 0; j < PT; j++) dA[j] = xr0[tid + j * NT];
#pragma unroll
  for (int j = 0; j < PT; j++) dB[j] = xr1[tid + j * NT];  // prefetch row 1

  process_row(dA, k, tid, lane, wid, hist1, hist2, hist3, cand, sel, &cnt,
              reinterpret_cast<u32x4*>(out + row0 * (size_t)ROWLEN));
  process_row(dB, k, tid, lane, wid, hist1, hist2, hist3, cand, sel, &cnt,
              reinterpret_cast<u32x4*>(out + (row0 + 1) * (size_t)ROWLEN));
}

extern "C" void kernel_launch(void* const* d_in, const int* in_sizes, int n_in,
                              void* d_out, int out_size, void* d_ws, size_t ws_size,
                              hipStream_t stream) {
  const float* x   = (const float*)d_in[0];
  const int*   kp  = (const int*)d_in[1];
  float*       out = (float*)d_out;
  const int rows = out_size / ROWLEN;  // 4096
  topk_act_kernel<<<rows / RPB, NT, 0, stream>>>(x, out, kp);
}